// Round 13
// baseline (724.870 us; speedup 1.0000x reference)
//
#include <hip/hip_runtime.h>

// ---------------- problem constants ----------------
#define B_ 4
#define N_ 96
#define C_ 256
#define NPAIR (B_*N_*N_)        // 36864 pair rows
#define CE (NPAIR*C_)           // 9437184 elements per qkv slab
#define SCALE 8.838834764831844f  // 50/sqrt(32)
#define CP 132                  // gemm C-stage LDS pitch (conflict-free)
// ws budget: 256 MiB (268.4 MB). Usage ~248 MB.
// Head-chunked layer pipeline (c=0: h 0-3, c=1: h 4-7) for L3 residency.
// xb is DOUBLE-BUFFERED: chunk-1's gemm must read the layer input, which
// chunk-0's attn would otherwise have overwritten (round-12 RAW hazard).

typedef __attribute__((ext_vector_type(4))) float f32x4;
typedef __attribute__((ext_vector_type(8))) __bf16 bf16x8;
typedef __attribute__((ext_vector_type(4))) __bf16 bf16x4;
typedef __attribute__((ext_vector_type(4))) unsigned short u16x4;
typedef __attribute__((ext_vector_type(8))) unsigned short u16x8;

__device__ __forceinline__ unsigned short f2bf(float f){
  __bf16 h = (__bf16)f;                      // RNE convert
  return __builtin_bit_cast(unsigned short, h);
}
__device__ __forceinline__ float bf2f(unsigned short u){
  union { unsigned int i; float f; } v; v.i = ((unsigned int)u) << 16; return v.f;
}
__device__ __forceinline__ f32x4 vmax4(f32x4 a, f32x4 b){
  f32x4 r; r.x=fmaxf(a.x,b.x); r.y=fmaxf(a.y,b.y); r.z=fmaxf(a.z,b.z); r.w=fmaxf(a.w,b.w); return r;
}

// async global->LDS, 16B per lane; lds dest = wave-uniform base + lane*16
__device__ __forceinline__ void gload16(const void* g, void* l){
  __builtin_amdgcn_global_load_lds((const __attribute__((address_space(1))) unsigned int*)g,
                                   (__attribute__((address_space(3))) unsigned int*)l,
                                   16, 0, 0);
}

// attn-grid decode: 1536 blocks, XCD-grouped (2 bh per XCD for L2 line sharing).
__device__ __forceinline__ void attn_decode(int L, int c, int& bh, int& sec){
  int virt = (L & 7)*192 + (L >> 3);
  int lbh = virt / 96; sec = virt - lbh*96;
  bh = ((lbh >> 2) << 3) + 4*c + (lbh & 3);
}

// ---------------- K_init: zero stats partials (512 f) + pool acc (1024 f) ----------------
__global__ __launch_bounds__(256) void k_init(float* __restrict__ z){
  for (int i = threadIdx.x; i < 1536; i += 256) z[i] = 0.f;
}

// ---------------- K0: xb = bf16(emb[adj]) + stats partials (fp32-accurate) ----------------
__global__ __launch_bounds__(256) void k_gather(const int* __restrict__ adj,
                                                const float* __restrict__ emb,
                                                unsigned short* __restrict__ xb,
                                                float2* __restrict__ part){
  int tid = threadIdx.x;
  int lp = tid >> 4, lane16 = tid & 15;
  int pair = blockIdx.x*16 + lp;
  int row = adj[pair];
  const f32x4* src = (const f32x4*)(emb + (size_t)row*C_);
  u16x4*       dst = (u16x4*)(xb + (size_t)pair*C_);
  float s = 0.f, q = 0.f;
  for (int v = 0; v < 4; ++v){
    f32x4 t = src[v*16 + lane16];
    u16x4 o;
    o.x = f2bf(t.x); o.y = f2bf(t.y); o.z = f2bf(t.z); o.w = f2bf(t.w);
    dst[v*16 + lane16] = o;
    s += t.x + t.y + t.z + t.w;
    q += t.x*t.x + t.y*t.y + t.z*t.z + t.w*t.w;
  }
  __shared__ float rs[256], rq[256];
  rs[tid] = s; rq[tid] = q; __syncthreads();
  for (int o = 128; o > 0; o >>= 1){
    if (tid < o){ rs[tid] += rs[tid+o]; rq[tid] += rq[tid+o]; }
    __syncthreads();
  }
  if (tid == 0){
    float* pp = (float*)&part[blockIdx.x & 63];
    atomicAdd(pp, rs[0]); atomicAdd(pp+1, rq[0]);
  }
}

// ---------------- K0b: weights fp32->bf16 + per-row fp32 sums (for norm folding) ----------------
__global__ __launch_bounds__(256) void k_wconv(const float* __restrict__ w,
                                               unsigned short* __restrict__ wb,
                                               float* __restrict__ wsum){
  int row  = blockIdx.x*4 + (threadIdx.x >> 6);
  int lane = threadIdx.x & 63;
  f32x4 v = ((const f32x4*)(w + (size_t)row*256))[lane];
  u16x4 o;
  o.x = f2bf(v.x); o.y = f2bf(v.y); o.z = f2bf(v.z); o.w = f2bf(v.w);
  ((u16x4*)(wb + (size_t)row*256))[lane] = o;
  float s = v.x + v.y + v.z + v.w;
  for (int m = 32; m > 0; m >>= 1) s += __shfl_down(s, m);
  if (lane == 0) wsum[row] = s;
}

// ---------------- K4: qkv GEMM, head-chunked (5 n-tiles), XCD-swizzled, folded norm ----------------
// 1440 blocks: xcd = L&7; rest = L>>3; n-tile = (rest%5)*2 + c; m-tile = xcd + 8*(rest/5).
__global__ __launch_bounds__(256) void k_gemm(const unsigned short* __restrict__ Xb,
                                              const unsigned short* __restrict__ W,
                                              const float* __restrict__ wsum_l,
                                              const float2* __restrict__ part,
                                              unsigned short* __restrict__ qkv5,
                                              int c){
  __shared__ unsigned short smem[128*CP];    // As|Bs carved during K-loop
  unsigned short* As = smem;
  unsigned short* Bs = smem + 128*64;
  const int tid = threadIdx.x;
  const int w = tid >> 6, lane = tid & 63;
  const int quad = lane >> 4, l16 = lane & 15;
  const int L = blockIdx.x;
  const int xcd = L & 7, rest = L >> 3;
  const int nt = (rest % 5)*2 + c, kt2 = rest / 5;
  const int m0 = (xcd + 8*kt2) * 128, n0 = nt * 128;
  const int mw = (w & 1) * 64, nw = (w >> 1) * 64;
  double S = 0.0, Q = 0.0;
  for (int i = 0; i < 64; ++i){ float2 pp = part[i]; S += (double)pp.x; Q += (double)pp.y; }
  const float mean = (float)(S / (double)CE);
  const float rstd = (float)(1.0 / sqrt((Q - S*S/(double)CE) / (double)(CE - 1)));
  f32x4 acc[4][4] = {};

  for (int kt = 0; kt < 256; kt += 64){
    const int rbase = w * 32;
    const int rowoff = lane >> 3;
    const int kg = (lane & 7) ^ rowoff;
    for (int i8 = 0; i8 < 4; ++i8){
      int row = rbase + i8*8 + rowoff;
      gload16(Xb + (size_t)(m0+row)*256 + kt + kg*8, &As[(rbase + i8*8)*64]);
      gload16(W  + (size_t)(n0+row)*256 + kt + kg*8, &Bs[(rbase + i8*8)*64]);
    }
    __syncthreads();
    for (int ks = 0; ks < 2; ++ks){
      bf16x8 af[4], bf[4];
      for (int t4 = 0; t4 < 4; ++t4){
        int rm = mw + t4*16 + l16;
        af[t4] = *(const bf16x8*)((const char*)As + rm*128 + ((((ks<<2)|quad) ^ (rm&7))*16));
        int rn = nw + t4*16 + l16;
        bf[t4] = *(const bf16x8*)((const char*)Bs + rn*128 + ((((ks<<2)|quad) ^ (rn&7))*16));
      }
      for (int mi = 0; mi < 4; ++mi)
        for (int ni = 0; ni < 4; ++ni)
          acc[mi][ni] = __builtin_amdgcn_mfma_f32_16x16x32_bf16(af[mi], bf[ni], acc[mi][ni], 0, 0, 0);
    }
    __syncthreads();
  }

  float ws[4];
  #pragma unroll
  for (int ni = 0; ni < 4; ++ni) ws[ni] = wsum_l[n0 + nw + ni*16 + l16];
  for (int mi = 0; mi < 4; ++mi)
    for (int ni = 0; ni < 4; ++ni)
      for (int r = 0; r < 4; ++r){
        int row = mw + mi*16 + quad*4 + r;
        int col = nw + ni*16 + l16;
        float val = rstd*(acc[mi][ni][r] - mean*ws[ni]);
        smem[row*CP + col] = f2bf(val);
      }
  __syncthreads();

  const int t_slab = n0 >> 8;
  const int hbase  = (n0 >> 5) & 7;
  unsigned short* slab = qkv5 + (size_t)t_slab*CE;
  const int trow = tid >> 4;
  const int tcol = (tid & 15) * 8;
  const int h  = hbase + (tcol >> 5);
  const int dd = tcol & 31;
  for (int pass = 0; pass < 8; ++pass){
    int row = pass*16 + trow;
    int gm = m0 + row;
    int b = gm / 9216; int rem = gm - b*9216;
    int ii = rem / 96, jj = rem - (rem/96)*96;
    u16x8 vv = *(const u16x8*)&smem[row*CP + tcol];
    *(u16x8*)&slab[(((size_t)(b*8+h)*96 + ii)*96 + jj)*32 + dd] = vv;
  }
}

// ---------------- K5: branch-1 scores; s1 layout [bh][j][i][p] (fp16); chunked ----------------
__global__ __launch_bounds__(256) void k_scores1(const unsigned short* __restrict__ qkv5,
                                                 unsigned short* __restrict__ s1,
                                                 int c){
  __shared__ unsigned short Qs[96*40], Ks[96*40];
  __shared__ unsigned short Ss[96*100];
  int bh, ic; attn_decode(blockIdx.x, c, bh, ic);   // ic = i
  int tid = threadIdx.x;
  size_t gslab = ((size_t)bh*96 + ic)*3072;
  const unsigned short* qp = qkv5 + 0*(size_t)CE + gslab;
  const unsigned short* kp = qkv5 + 1*(size_t)CE + gslab;
  for (int g = tid; g < 768; g += 256){
    int j = g >> 3, q4 = g & 7;
    *(u16x4*)&Qs[j*40 + q4*4] = *(const u16x4*)&qp[j*32 + q4*4];
    *(u16x4*)&Ks[j*40 + q4*4] = *(const u16x4*)&kp[j*32 + q4*4];
  }
  __syncthreads();
  int w = tid >> 6, lane = tid & 63, quad = lane >> 4, l16 = lane & 15;
  #pragma unroll
  for (int r = 0; r < 9; ++r){
    int tile = w*9 + r; int jt = tile/6, pt = tile - jt*6;
    bf16x8 a = *(const bf16x8*)((const char*)Qs + (jt*16 + l16)*80 + quad*16);
    bf16x8 b = *(const bf16x8*)((const char*)Ks + (pt*16 + l16)*80 + quad*16);
    f32x4 cc = {0.f,0.f,0.f,0.f};
    cc = __builtin_amdgcn_mfma_f32_16x16x32_bf16(a, b, cc, 0, 0, 0);
    int col = pt*16 + l16;
    #pragma unroll
    for (int rr = 0; rr < 4; ++rr){
      int row = jt*16 + quad*4 + rr;
      _Float16 hv = (_Float16)(cc[rr] * SCALE);
      Ss[row*100 + col] = __builtin_bit_cast(unsigned short, hv);
    }
  }
  __syncthreads();
  for (int g = tid; g < 1152; g += 256){
    int j = g / 12, c8 = g - j*12;
    *(u16x8*)&s1[((size_t)(bh*96 + j))*9216 + ic*96 + c8*8] = *(const u16x8*)&Ss[j*100 + c8*8];
  }
}

// ---------------- K6: branch-2 scores + register softmax + O2, per (bh, jj); chunked ----------------
// Reads qkv5/s1; STORES O2 to xout (never reads xout).
__global__ __launch_bounds__(256) void k_attn2(const unsigned short* __restrict__ qkv5,
                                               const unsigned short* __restrict__ s1,
                                               unsigned short* __restrict__ a_out,
                                               unsigned short* __restrict__ xout,
                                               float* __restrict__ poolAcc,
                                               int last, int c){
  __shared__ unsigned short Qs[96*40];       // phase1: Q rows; phase2: Vd alias
  __shared__ unsigned short Ks[96*40];
  __shared__ unsigned short SsPb[96*104];    // phase1: s1 pitch 96; phase2: probs bf16 pitch 104
  __shared__ float Mx[192], Sx[192];
  __shared__ float poolL[32];
  unsigned short* Vd = Qs;                   // alias (disjoint lifetime)
  int bh, jj; attn_decode(blockIdx.x, c, bh, jj);
  int b = bh >> 3, h = bh & 7;
  int tid = threadIdx.x;
  int w = tid >> 6, lane = tid & 63, quad = lane >> 4, l16 = lane & 15;
  const unsigned short* qn  = qkv5 + 0*(size_t)CE;
  const unsigned short* k2n = qkv5 + 2*(size_t)CE;
  const unsigned short* v2n = qkv5 + 4*(size_t)CE;
  if (tid < 192){ Mx[tid] = -1e30f; Sx[tid] = 0.f; }
  if (tid < 32) poolL[tid] = 0.f;
  // async stage s1 (contiguous 18432B -> 18 x 1024B wave-chunks, linear pitch 96)
  const unsigned short* s1g = s1 + ((size_t)bh*96 + jj)*9216;
  for (int k = w; k < 18; k += 4)
    gload16(s1g + k*512 + lane*8, &SsPb[k*512]);
  // stage Q/K2 (q4-major lane map); V2 deferred
  for (int g = tid; g < 768; g += 256){
    int r7 = g & 7, q4 = (g >> 3) & 7, a8 = g >> 6;
    int p = r7 + a8*8;
    size_t base = (((size_t)bh*96 + p)*96 + jj)*32 + q4*4;
    *(u16x4*)&Qs[p*40 + q4*4] = *(const u16x4*)&qn[base];
    *(u16x4*)&Ks[p*40 + q4*4] = *(const u16x4*)&k2n[base];
  }
  __syncthreads();
  f32x4 sc[9];
  #pragma unroll
  for (int r = 0; r < 9; ++r){
    int tile = w*9 + r; int it = tile/6, pt = tile - it*6;
    bf16x8 a = *(const bf16x8*)((const char*)Qs + (it*16 + l16)*80 + quad*16);
    bf16x8 bb = *(const bf16x8*)((const char*)Ks + (pt*16 + l16)*80 + quad*16);
    f32x4 cc = {0.f,0.f,0.f,0.f};
    cc = __builtin_amdgcn_mfma_f32_16x16x32_bf16(a, bb, cc, 0, 0, 0);
    int col = pt*16 + l16;
    #pragma unroll
    for (int rr = 0; rr < 4; ++rr){
      int row = it*16 + quad*4 + rr;
      _Float16 hv = __builtin_bit_cast(_Float16, SsPb[row*96 + col]);
      sc[r][rr] = cc[rr]*SCALE + (float)hv;
    }
  }
  const bool odd = (w & 1);
  const int itA = (w*9)/6, itB = itA + 1;
  const int slot = w & 1;
  f32x4 vA = {-1e30f,-1e30f,-1e30f,-1e30f}, vB = vA;
  #pragma unroll
  for (int r = 0; r < 9; ++r){
    bool inA = odd ? (r < 3) : (r < 6);
    if (inA) vA = vmax4(vA, sc[r]); else vB = vmax4(vB, sc[r]);
  }
  #pragma unroll
  for (int m = 1; m < 16; m <<= 1){
    f32x4 t;
    t.x=__shfl_xor(vA.x,m); t.y=__shfl_xor(vA.y,m); t.z=__shfl_xor(vA.z,m); t.w=__shfl_xor(vA.w,m);
    vA = vmax4(vA, t);
    t.x=__shfl_xor(vB.x,m); t.y=__shfl_xor(vB.y,m); t.z=__shfl_xor(vB.z,m); t.w=__shfl_xor(vB.w,m);
    vB = vmax4(vB, t);
  }
  if (l16 < 4){
    float va = (l16==0)?vA.x:(l16==1)?vA.y:(l16==2)?vA.z:vA.w;
    float vb = (l16==0)?vB.x:(l16==1)?vB.y:(l16==2)?vB.z:vB.w;
    Mx[(itA*16 + quad*4 + l16)*2 + slot] = va;
    Mx[(itB*16 + quad*4 + l16)*2 + slot] = vb;
  }
  __syncthreads();                            // all Qs/Ks reads complete here
  // late-stage V2 into the Qs alias (overlaps with softmax below)
  for (int g = tid; g < 768; g += 256){
    int r7 = g & 7, q4 = (g >> 3) & 7, a8 = g >> 6;
    int p = r7 + a8*8;
    u16x4 v = *(const u16x4*)&v2n[(((size_t)bh*96 + p)*96 + jj)*32 + q4*4];
    int d0 = q4*4;
    Vd[(d0+0)*100 + p] = v.x; Vd[(d0+1)*100 + p] = v.y;
    Vd[(d0+2)*100 + p] = v.z; Vd[(d0+3)*100 + p] = v.w;
  }
  f32x4 mA, mB;
  #pragma unroll
  for (int rr = 0; rr < 4; ++rr){
    float2 ta = *(const float2*)&Mx[(itA*16 + quad*4 + rr)*2];
    float2 tb = *(const float2*)&Mx[(itB*16 + quad*4 + rr)*2];
    mA[rr] = fmaxf(ta.x, ta.y); mB[rr] = fmaxf(tb.x, tb.y);
  }
  f32x4 sA = {0.f,0.f,0.f,0.f}, sB = {0.f,0.f,0.f,0.f};
  #pragma unroll
  for (int r = 0; r < 9; ++r){
    bool inA = odd ? (r < 3) : (r < 6);
    #pragma unroll
    for (int rr = 0; rr < 4; ++rr){
      float m = inA ? mA[rr] : mB[rr];
      float e = __expf(sc[r][rr] - m);
      sc[r][rr] = e;
      if (inA) sA[rr] += e; else sB[rr] += e;
    }
  }
  #pragma unroll
  for (int m = 1; m < 16; m <<= 1){
    f32x4 t;
    t.x=__shfl_xor(sA.x,m); t.y=__shfl_xor(sA.y,m); t.z=__shfl_xor(sA.z,m); t.w=__shfl_xor(sA.w,m);
    sA += t;
    t.x=__shfl_xor(sB.x,m); t.y=__shfl_xor(sB.y,m); t.z=__shfl_xor(sB.z,m); t.w=__shfl_xor(sB.w,m);
    sB += t;
  }
  if (l16 < 4){
    float va = (l16==0)?sA.x:(l16==1)?sA.y:(l16==2)?sA.z:sA.w;
    float vb = (l16==0)?sB.x:(l16==1)?sB.y:(l16==2)?sB.z:sB.w;
    Sx[(itA*16 + quad*4 + l16)*2 + slot] = va;
    Sx[(itB*16 + quad*4 + l16)*2 + slot] = vb;
  }
  __syncthreads();                            // Vd writes fenced here
  f32x4 iA, iB;
  #pragma unroll
  for (int rr = 0; rr < 4; ++rr){
    float2 ta = *(const float2*)&Sx[(itA*16 + quad*4 + rr)*2];
    float2 tb = *(const float2*)&Sx[(itB*16 + quad*4 + rr)*2];
    iA[rr] = 1.f/(ta.x + ta.y); iB[rr] = 1.f/(tb.x + tb.y);
  }
  // probs into shared buffer (pitch 104)
  #pragma unroll
  for (int r = 0; r < 9; ++r){
    int tile = w*9 + r; int it = tile/6, pt = tile - it*6;
    int col = pt*16 + l16;
    bool inA = odd ? (r < 3) : (r < 6);
    #pragma unroll
    for (int rr = 0; rr < 4; ++rr){
      int row = it*16 + quad*4 + rr;
      float inv = inA ? iA[rr] : iB[rr];
      SsPb[row*104 + col] = f2bf(sc[r][rr] * inv);
    }
  }
  __syncthreads();
  // write probs [bh][i][j=jj][p]: 96 strided full-line 192B chunks
  unsigned short* ap = a_out + (size_t)bh*96*9216 + (size_t)jj*96;
  for (int g = tid; g < 1152; g += 256){
    int i = g / 12, cc = g - i*12;
    *(u16x8*)&ap[(size_t)i*9216 + cc*8] = *(const u16x8*)&SsPb[i*104 + cc*8];
  }
  // O2 = P(96i x 96p) @ V2(96p x 32d)
  #pragma unroll
  for (int r = 0; r < 3; ++r){
    int tile = w*3 + r; int it = tile >> 1, dt = tile & 1;
    f32x4 cc = {0.f,0.f,0.f,0.f};
    #pragma unroll
    for (int kp3 = 0; kp3 < 3; ++kp3){
      bf16x8 a = *(const bf16x8*)((const char*)SsPb + (it*16 + l16)*208 + kp3*64 + quad*16);
      const char* vb = (const char*)Vd + (dt*16 + l16)*200 + kp3*64 + quad*16;
      bf16x4 lo = *(const bf16x4*)vb;
      bf16x4 hi = *(const bf16x4*)(vb + 8);
      bf16x8 bb = __builtin_shufflevector(lo, hi, 0,1,2,3,4,5,6,7);
      cc = __builtin_amdgcn_mfma_f32_16x16x32_bf16(a, bb, cc, 0, 0, 0);
    }
    int d = dt*16 + l16;
    if (!last){
      #pragma unroll
      for (int rr = 0; rr < 4; ++rr){
        int i = it*16 + quad*4 + rr;
        xout[(((size_t)b*96 + i)*96 + jj)*256 + h*32 + d] = f2bf(cc[rr]);
      }
    } else {
      atomicAdd(&poolL[d], cc[0] + cc[1] + cc[2] + cc[3]);
    }
  }
  if (last){
    __syncthreads();
    if (tid < 32) atomicAdd(&poolAcc[b*256 + h*32 + tid], poolL[tid]);
  }
}

// ---------------- K7: O1 per (bh, ii); chunked; xout += O1; last==1: pool only ----------------
__global__ __launch_bounds__(256) void k_attn1(const unsigned short* __restrict__ a_in,
                                               const unsigned short* __restrict__ qkv5,
                                               unsigned short* __restrict__ xout,
                                               float2* __restrict__ statsPart,
                                               float* __restrict__ poolAcc,
                                               int last, int c){
  __shared__ unsigned short As[96*104], Vd[32*100];
  __shared__ float redS[256], redQ[256];
  __shared__ float poolL[32];
  int bh, ii; attn_decode(blockIdx.x, c, bh, ii);
  int b = bh >> 3, h = bh & 7;
  int tid = threadIdx.x;
  if (tid < 32) poolL[tid] = 0.f;
  const unsigned short* vp = qkv5 + 3*(size_t)CE + ((size_t)bh*96 + ii)*3072;
  for (int g = tid; g < 768; g += 256){
    int r7 = g & 7, q4 = (g >> 3) & 7, a8 = g >> 6;
    int p = r7 + a8*8;
    u16x4 v = *(const u16x4*)&vp[p*32 + q4*4];
    int d0 = q4*4;
    Vd[(d0+0)*100 + p] = v.x; Vd[(d0+1)*100 + p] = v.y;
    Vd[(d0+2)*100 + p] = v.z; Vd[(d0+3)*100 + p] = v.w;
  }
  const unsigned short* ain = a_in + ((size_t)bh*96 + ii)*9216;   // contiguous
  for (int g = tid; g < 1152; g += 256){
    int j = g / 12, cc = g - j*12;
    *(u16x8*)&As[j*104 + cc*8] = *(const u16x8*)&ain[j*96 + cc*8];
  }
  __syncthreads();
  int w = tid >> 6, lane = tid & 63, quad = lane >> 4, l16 = lane & 15;
  float ls = 0.f, lq = 0.f;
  #pragma unroll
  for (int r = 0; r < 3; ++r){
    int tile = w*3 + r; int jt = tile >> 1, dt = tile & 1;
    f32x4 cc = {0.f,0.f,0.f,0.f};
    #pragma unroll
    for (int kp3 = 0; kp3 < 3; ++kp3){
      bf16x8 a = *(const bf16x8*)((const char*)As + (jt*16 + l16)*208 + kp3*64 + quad*16);
      const char* vb = (const char*)Vd + (dt*16 + l16)*200 + kp3*64 + quad*16;
      bf16x4 lo = *(const bf16x4*)vb;
      bf16x4 hi = *(const bf16x4*)(vb + 8);
      bf16x8 bb = __builtin_shufflevector(lo, hi, 0,1,2,3,4,5,6,7);
      cc = __builtin_amdgcn_mfma_f32_16x16x32_bf16(a, bb, cc, 0, 0, 0);
    }
    int d = dt*16 + l16;
    if (!last){
      #pragma unroll
      for (int rr = 0; rr < 4; ++rr){
        int j = jt*16 + quad*4 + rr;
        size_t xi = (((size_t)b*96 + ii)*96 + j)*256 + h*32 + d;
        float val = bf2f(xout[xi]) + cc[rr];
        xout[xi] = f2bf(val); ls += val; lq += val*val;
      }
    } else {
      atomicAdd(&poolL[d], cc[0] + cc[1] + cc[2] + cc[3]);
    }
  }
  if (!last){
    redS[tid] = ls; redQ[tid] = lq; __syncthreads();
    for (int o = 128; o > 0; o >>= 1){
      if (tid < o){ redS[tid] += redS[tid+o]; redQ[tid] += redQ[tid+o]; }
      __syncthreads();
    }
    if (tid == 0){
      float* pp = (float*)&statsPart[blockIdx.x & 63];
      atomicAdd(pp, redS[0]); atomicAdd(pp+1, redQ[0]);
    }
  } else {
    __syncthreads();
    if (tid < 32) atomicAdd(&poolAcc[b*256 + h*32 + tid], poolL[tid]);
  }
}

// ---------------- K9: head ----------------
__global__ __launch_bounds__(256) void k_head(const float* __restrict__ poolAcc,
                                              const float* __restrict__ hw,
                                              const float* __restrict__ hb,
                                              float* __restrict__ out){
  int b = blockIdx.x, t = threadIdx.x;
  __shared__ float xm[256];
  xm[t] = poolAcc[b*256 + t] * (1.0f/9216.0f);
  __syncthreads();
  float o = hb[t];
  for (int cc = 0; cc < 256; ++cc) o += xm[cc] * hw[t*256 + cc];
  out[b*256 + t] = o;
}

// ---------------- launch ----------------
extern "C" void kernel_launch(void* const* d_in, const int* in_sizes, int n_in,
                              void* d_out, int out_size, void* d_ws, size_t ws_size,
                              hipStream_t stream){
  (void)in_sizes; (void)n_in; (void)out_size; (void)ws_size;
  const int*   adj  = (const int*)d_in[0];
  const float* emb  = (const float*)d_in[1];
  const float* qkvw = (const float*)d_in[2];
  const float* hw   = (const float*)d_in[3];
  const float* hb   = (const float*)d_in[4];

  char* p = (char*)d_ws;
  unsigned short* xb0  = (unsigned short*)p; p += (size_t)CE*2;            //  18.87 MB
  unsigned short* xb1  = (unsigned short*)p; p += (size_t)CE*2;            //  18.87 MB
  unsigned short* qkv5 = (unsigned short*)p; p += (size_t)5*CE*2;          //  94.37 MB
  unsigned short* s1   = (unsigned short*)p; p += (size_t)32*96*9216*2;    //  56.62 MB
  unsigned short* aP   = (unsigned short*)p; p += (size_t)32*96*9216*2;    //  56.62 MB
  unsigned short* wbf  = (unsigned short*)p; p += (size_t)4*1280*256*2;    //   2.62 MB
  float*          wsum = (float*)p;          p += (size_t)4*1280*4;        //  20 KB
  float2*         part = (float2*)p;         p += 4*64*sizeof(float2);
  float*          pool = (float*)p;          p += 1024*sizeof(float);

  k_init  <<<dim3(1),     dim3(256), 0, stream>>>((float*)part);
  k_gather<<<dim3(2304),  dim3(256), 0, stream>>>(adj, emb, xb0, part);
  k_wconv <<<dim3(1280),  dim3(256), 0, stream>>>(qkvw, wbf, wsum);
  for (int l = 0; l < 4; ++l){
    int last = (l == 3) ? 1 : 0;
    unsigned short* xin  = (l & 1) ? xb1 : xb0;
    unsigned short* xout = (l & 1) ? xb0 : xb1;
    for (int c = 0; c < 2; ++c){
      k_gemm   <<<dim3(1440), dim3(256), 0, stream>>>(xin, wbf + (size_t)l*1280*256,
                                                      wsum + l*1280, part + l*64, qkv5, c);
      k_scores1<<<dim3(1536), dim3(256), 0, stream>>>(qkv5, s1, c);
      k_attn2  <<<dim3(1536), dim3(256), 0, stream>>>(qkv5, s1, aP, xout, pool, last, c);
      k_attn1  <<<dim3(1536), dim3(256), 0, stream>>>(aP, qkv5, xout,
                                                      part + (l+1 < 4 ? (l+1)*64 : 0),
                                                      pool, last, c);
    }
  }
  k_head<<<dim3(4), dim3(256), 0, stream>>>(pool, hw, hb, (float*)d_out);
}

// Round 14
// 638.555 us; speedup vs baseline: 1.1352x; 1.1352x over previous
//
#include <hip/hip_runtime.h>

// ---------------- problem constants ----------------
#define B_ 4
#define N_ 96
#define C_ 256
#define NPAIR (B_*N_*N_)        // 36864 pair rows
#define CE (NPAIR*C_)           // 9437184 elements per qkv slab
#define SCALE 8.838834764831844f  // 50/sqrt(32)
#define CP 132                  // gemm C-stage LDS pitch (conflict-free)
// ws budget: 256 MiB. Usage ~229 MB. (Round-11 structure; r12/r13 chunking reverted.)

typedef __attribute__((ext_vector_type(4))) float f32x4;
typedef __attribute__((ext_vector_type(8))) __bf16 bf16x8;
typedef __attribute__((ext_vector_type(4))) __bf16 bf16x4;
typedef __attribute__((ext_vector_type(4))) unsigned short u16x4;
typedef __attribute__((ext_vector_type(8))) unsigned short u16x8;

__device__ __forceinline__ unsigned short f2bf(float f){
  __bf16 h = (__bf16)f;                      // RNE convert
  return __builtin_bit_cast(unsigned short, h);
}
__device__ __forceinline__ float bf2f(unsigned short u){
  union { unsigned int i; float f; } v; v.i = ((unsigned int)u) << 16; return v.f;
}
__device__ __forceinline__ f32x4 vmax4(f32x4 a, f32x4 b){
  f32x4 r; r.x=fmaxf(a.x,b.x); r.y=fmaxf(a.y,b.y); r.z=fmaxf(a.z,b.z); r.w=fmaxf(a.w,b.w); return r;
}

// async global->LDS, 16B per lane; lds dest = wave-uniform base + lane*16
__device__ __forceinline__ void gload16(const void* g, void* l){
  __builtin_amdgcn_global_load_lds((const __attribute__((address_space(1))) unsigned int*)g,
                                   (__attribute__((address_space(3))) unsigned int*)l,
                                   16, 0, 0);
}

// ---------------- K_init: zero stats partials (512 f) + pool acc (1024 f) ----------------
__global__ __launch_bounds__(256) void k_init(float* __restrict__ z){
  for (int i = threadIdx.x; i < 1536; i += 256) z[i] = 0.f;
}

// ---------------- K0: xb = bf16(emb[adj]) + stats partials (fp32-accurate) ----------------
__global__ __launch_bounds__(256) void k_gather(const int* __restrict__ adj,
                                                const float* __restrict__ emb,
                                                unsigned short* __restrict__ xb,
                                                float2* __restrict__ part){
  int tid = threadIdx.x;
  int lp = tid >> 4, lane16 = tid & 15;
  int pair = blockIdx.x*16 + lp;
  int row = adj[pair];
  const f32x4* src = (const f32x4*)(emb + (size_t)row*C_);
  u16x4*       dst = (u16x4*)(xb + (size_t)pair*C_);
  float s = 0.f, q = 0.f;
  for (int v = 0; v < 4; ++v){
    f32x4 t = src[v*16 + lane16];
    u16x4 o;
    o.x = f2bf(t.x); o.y = f2bf(t.y); o.z = f2bf(t.z); o.w = f2bf(t.w);
    dst[v*16 + lane16] = o;
    s += t.x + t.y + t.z + t.w;
    q += t.x*t.x + t.y*t.y + t.z*t.z + t.w*t.w;
  }
  __shared__ float rs[256], rq[256];
  rs[tid] = s; rq[tid] = q; __syncthreads();
  for (int o = 128; o > 0; o >>= 1){
    if (tid < o){ rs[tid] += rs[tid+o]; rq[tid] += rq[tid+o]; }
    __syncthreads();
  }
  if (tid == 0){
    float* pp = (float*)&part[blockIdx.x & 63];
    atomicAdd(pp, rs[0]); atomicAdd(pp+1, rq[0]);
  }
}

// ---------------- K0b: weights fp32->bf16 + per-row fp32 sums (for norm folding) ----------------
__global__ __launch_bounds__(256) void k_wconv(const float* __restrict__ w,
                                               unsigned short* __restrict__ wb,
                                               float* __restrict__ wsum){
  int row  = blockIdx.x*4 + (threadIdx.x >> 6);
  int lane = threadIdx.x & 63;
  f32x4 v = ((const f32x4*)(w + (size_t)row*256))[lane];
  u16x4 o;
  o.x = f2bf(v.x); o.y = f2bf(v.y); o.z = f2bf(v.z); o.w = f2bf(v.w);
  ((u16x4*)(wb + (size_t)row*256))[lane] = o;
  float s = v.x + v.y + v.z + v.w;
  for (int m = 32; m > 0; m >>= 1) s += __shfl_down(s, m);
  if (lane == 0) wsum[row] = s;
}

// ---------------- K4: qkv GEMM, XCD-swizzled grid, folded norm, LDS-staged epilogue ----------------
__global__ __launch_bounds__(256) void k_gemm(const unsigned short* __restrict__ Xb,
                                              const unsigned short* __restrict__ W,
                                              const float* __restrict__ wsum_l,
                                              const float2* __restrict__ part,
                                              unsigned short* __restrict__ qkv5){
  __shared__ unsigned short smem[128*CP];    // As|Bs carved during K-loop
  unsigned short* As = smem;
  unsigned short* Bs = smem + 128*64;
  const int tid = threadIdx.x;
  const int w = tid >> 6, lane = tid & 63;
  const int quad = lane >> 4, l16 = lane & 15;
  const int L = blockIdx.x;
  const int xcd = L & 7, rest = L >> 3;
  const int nt = rest % 10, kt2 = rest / 10;
  const int m0 = (xcd + 8*kt2) * 128, n0 = nt * 128;
  const int mw = (w & 1) * 64, nw = (w >> 1) * 64;
  double S = 0.0, Q = 0.0;
  for (int i = 0; i < 64; ++i){ float2 pp = part[i]; S += (double)pp.x; Q += (double)pp.y; }
  const float mean = (float)(S / (double)CE);
  const float rstd = (float)(1.0 / sqrt((Q - S*S/(double)CE) / (double)(CE - 1)));
  f32x4 acc[4][4] = {};

  for (int kt = 0; kt < 256; kt += 64){
    const int rbase = w * 32;
    const int rowoff = lane >> 3;
    const int kg = (lane & 7) ^ rowoff;
    for (int i8 = 0; i8 < 4; ++i8){
      int row = rbase + i8*8 + rowoff;
      gload16(Xb + (size_t)(m0+row)*256 + kt + kg*8, &As[(rbase + i8*8)*64]);
      gload16(W  + (size_t)(n0+row)*256 + kt + kg*8, &Bs[(rbase + i8*8)*64]);
    }
    __syncthreads();
    for (int ks = 0; ks < 2; ++ks){
      bf16x8 af[4], bf[4];
      for (int t4 = 0; t4 < 4; ++t4){
        int rm = mw + t4*16 + l16;
        af[t4] = *(const bf16x8*)((const char*)As + rm*128 + ((((ks<<2)|quad) ^ (rm&7))*16));
        int rn = nw + t4*16 + l16;
        bf[t4] = *(const bf16x8*)((const char*)Bs + rn*128 + ((((ks<<2)|quad) ^ (rn&7))*16));
      }
      for (int mi = 0; mi < 4; ++mi)
        for (int ni = 0; ni < 4; ++ni)
          acc[mi][ni] = __builtin_amdgcn_mfma_f32_16x16x32_bf16(af[mi], bf[ni], acc[mi][ni], 0, 0, 0);
    }
    __syncthreads();
  }

  float ws[4];
  #pragma unroll
  for (int ni = 0; ni < 4; ++ni) ws[ni] = wsum_l[n0 + nw + ni*16 + l16];
  for (int mi = 0; mi < 4; ++mi)
    for (int ni = 0; ni < 4; ++ni)
      for (int r = 0; r < 4; ++r){
        int row = mw + mi*16 + quad*4 + r;
        int col = nw + ni*16 + l16;
        float val = rstd*(acc[mi][ni][r] - mean*ws[ni]);
        smem[row*CP + col] = f2bf(val);
      }
  __syncthreads();

  const int t_slab = n0 >> 8;
  const int hbase  = (n0 >> 5) & 7;
  unsigned short* slab = qkv5 + (size_t)t_slab*CE;
  const int trow = tid >> 4;
  const int tcol = (tid & 15) * 8;
  const int h  = hbase + (tcol >> 5);
  const int dd = tcol & 31;
  for (int pass = 0; pass < 8; ++pass){
    int row = pass*16 + trow;
    int gm = m0 + row;
    int b = gm / 9216; int rem = gm - b*9216;
    int ii = rem / 96, jj = rem - (rem/96)*96;
    u16x8 vv = *(const u16x8*)&smem[row*CP + tcol];
    *(u16x8*)&slab[(((size_t)(b*8+h)*96 + ii)*96 + jj)*32 + dd] = vv;
  }
}

// ---------------- K5: branch-1 scores; s1 layout [bh][j][i][p] (fp16) ----------------
__global__ __launch_bounds__(256) void k_scores1(const unsigned short* __restrict__ qkv5,
                                                 unsigned short* __restrict__ s1){
  __shared__ unsigned short Qs[96*40], Ks[96*40];
  __shared__ unsigned short Ss[96*100];
  int wg = blockIdx.x; int bh = wg/96, ic = wg - bh*96;   // ic = i
  int tid = threadIdx.x;
  size_t gslab = (size_t)wg*3072;
  const unsigned short* qp = qkv5 + 0*(size_t)CE + gslab;
  const unsigned short* kp = qkv5 + 1*(size_t)CE + gslab;
  for (int g = tid; g < 768; g += 256){
    int j = g >> 3, q4 = g & 7;
    *(u16x4*)&Qs[j*40 + q4*4] = *(const u16x4*)&qp[j*32 + q4*4];
    *(u16x4*)&Ks[j*40 + q4*4] = *(const u16x4*)&kp[j*32 + q4*4];
  }
  __syncthreads();
  int w = tid >> 6, lane = tid & 63, quad = lane >> 4, l16 = lane & 15;
  #pragma unroll
  for (int r = 0; r < 9; ++r){
    int tile = w*9 + r; int jt = tile/6, pt = tile - jt*6;
    bf16x8 a = *(const bf16x8*)((const char*)Qs + (jt*16 + l16)*80 + quad*16);
    bf16x8 b = *(const bf16x8*)((const char*)Ks + (pt*16 + l16)*80 + quad*16);
    f32x4 cc = {0.f,0.f,0.f,0.f};
    cc = __builtin_amdgcn_mfma_f32_16x16x32_bf16(a, b, cc, 0, 0, 0);
    int col = pt*16 + l16;
    #pragma unroll
    for (int rr = 0; rr < 4; ++rr){
      int row = jt*16 + quad*4 + rr;
      _Float16 hv = (_Float16)(cc[rr] * SCALE);
      Ss[row*100 + col] = __builtin_bit_cast(unsigned short, hv);
    }
  }
  __syncthreads();
  for (int g = tid; g < 1152; g += 256){
    int j = g / 12, c8 = g - j*12;
    *(u16x8*)&s1[((size_t)(bh*96 + j))*9216 + ic*96 + c8*8] = *(const u16x8*)&Ss[j*100 + c8*8];
  }
}

// ---------------- K6: branch-2 scores + register softmax + O2, per (bh, jj) ----------------
// s1 staged manually at pitch 100 -> sc-loop reads are bank-conflict-free
// (pitch 96 + gload16 had 192-word quad stride = 4-way conflicts).
__global__ __launch_bounds__(256) void k_attn2(const unsigned short* __restrict__ qkv5,
                                               const unsigned short* __restrict__ s1,
                                               unsigned short* __restrict__ a_out,
                                               unsigned short* __restrict__ xb,
                                               float* __restrict__ poolAcc,
                                               int last){
  __shared__ unsigned short Qs[96*40];       // phase1: Q rows; phase2: Vd alias
  __shared__ unsigned short Ks[96*40];
  __shared__ unsigned short SsPb[96*104];    // phase1: s1 pitch 100; phase2: probs bf16 pitch 104
  __shared__ float Mx[192], Sx[192];
  __shared__ float poolL[32];
  unsigned short* Vd = Qs;                   // alias (disjoint lifetime)
  int wg = blockIdx.x; int bh = wg/96, jj = wg - bh*96;
  int b = bh >> 3, h = bh & 7;
  int tid = threadIdx.x;
  int w = tid >> 6, lane = tid & 63, quad = lane >> 4, l16 = lane & 15;
  const unsigned short* qn  = qkv5 + 0*(size_t)CE;
  const unsigned short* k2n = qkv5 + 2*(size_t)CE;
  const unsigned short* v2n = qkv5 + 4*(size_t)CE;
  if (tid < 192){ Mx[tid] = -1e30f; Sx[tid] = 0.f; }
  if (tid < 32) poolL[tid] = 0.f;
  // stage s1 (contiguous 18432B) -> LDS pitch 100 (rows are exactly 12 u16x8 chunks)
  const unsigned short* s1g = s1 + ((size_t)bh*96 + jj)*9216;
  for (int g = tid; g < 1152; g += 256){
    int i = g / 12, c8 = g - i*12;
    *(u16x8*)&SsPb[i*100 + c8*8] = *(const u16x8*)&s1g[i*96 + c8*8];
  }
  // stage Q/K2 (q4-major lane map); V2 deferred
  for (int g = tid; g < 768; g += 256){
    int r7 = g & 7, q4 = (g >> 3) & 7, a8 = g >> 6;
    int p = r7 + a8*8;
    size_t base = (((size_t)bh*96 + p)*96 + jj)*32 + q4*4;
    *(u16x4*)&Qs[p*40 + q4*4] = *(const u16x4*)&qn[base];
    *(u16x4*)&Ks[p*40 + q4*4] = *(const u16x4*)&k2n[base];
  }
  __syncthreads();
  f32x4 sc[9];
  #pragma unroll
  for (int r = 0; r < 9; ++r){
    int tile = w*9 + r; int it = tile/6, pt = tile - it*6;
    bf16x8 a = *(const bf16x8*)((const char*)Qs + (it*16 + l16)*80 + quad*16);
    bf16x8 bb = *(const bf16x8*)((const char*)Ks + (pt*16 + l16)*80 + quad*16);
    f32x4 cc = {0.f,0.f,0.f,0.f};
    cc = __builtin_amdgcn_mfma_f32_16x16x32_bf16(a, bb, cc, 0, 0, 0);
    int col = pt*16 + l16;
    #pragma unroll
    for (int rr = 0; rr < 4; ++rr){
      int row = it*16 + quad*4 + rr;
      _Float16 hv = __builtin_bit_cast(_Float16, SsPb[row*100 + col]);
      sc[r][rr] = cc[rr]*SCALE + (float)hv;
    }
  }
  const bool odd = (w & 1);
  const int itA = (w*9)/6, itB = itA + 1;
  const int slot = w & 1;
  f32x4 vA = {-1e30f,-1e30f,-1e30f,-1e30f}, vB = vA;
  #pragma unroll
  for (int r = 0; r < 9; ++r){
    bool inA = odd ? (r < 3) : (r < 6);
    if (inA) vA = vmax4(vA, sc[r]); else vB = vmax4(vB, sc[r]);
  }
  #pragma unroll
  for (int m = 1; m < 16; m <<= 1){
    f32x4 t;
    t.x=__shfl_xor(vA.x,m); t.y=__shfl_xor(vA.y,m); t.z=__shfl_xor(vA.z,m); t.w=__shfl_xor(vA.w,m);
    vA = vmax4(vA, t);
    t.x=__shfl_xor(vB.x,m); t.y=__shfl_xor(vB.y,m); t.z=__shfl_xor(vB.z,m); t.w=__shfl_xor(vB.w,m);
    vB = vmax4(vB, t);
  }
  if (l16 < 4){
    float va = (l16==0)?vA.x:(l16==1)?vA.y:(l16==2)?vA.z:vA.w;
    float vb = (l16==0)?vB.x:(l16==1)?vB.y:(l16==2)?vB.z:vB.w;
    Mx[(itA*16 + quad*4 + l16)*2 + slot] = va;
    Mx[(itB*16 + quad*4 + l16)*2 + slot] = vb;
  }
  __syncthreads();                            // all Qs/Ks reads complete here
  // late-stage V2 into the Qs alias (overlaps with softmax below)
  for (int g = tid; g < 768; g += 256){
    int r7 = g & 7, q4 = (g >> 3) & 7, a8 = g >> 6;
    int p = r7 + a8*8;
    u16x4 v = *(const u16x4*)&v2n[(((size_t)bh*96 + p)*96 + jj)*32 + q4*4];
    int d0 = q4*4;
    Vd[(d0+0)*100 + p] = v.x; Vd[(d0+1)*100 + p] = v.y;
    Vd[(d0+2)*100 + p] = v.z; Vd[(d0+3)*100 + p] = v.w;
  }
  f32x4 mA, mB;
  #pragma unroll
  for (int rr = 0; rr < 4; ++rr){
    float2 ta = *(const float2*)&Mx[(itA*16 + quad*4 + rr)*2];
    float2 tb = *(const float2*)&Mx[(itB*16 + quad*4 + rr)*2];
    mA[rr] = fmaxf(ta.x, ta.y); mB[rr] = fmaxf(tb.x, tb.y);
  }
  f32x4 sA = {0.f,0.f,0.f,0.f}, sB = {0.f,0.f,0.f,0.f};
  #pragma unroll
  for (int r = 0; r < 9; ++r){
    bool inA = odd ? (r < 3) : (r < 6);
    #pragma unroll
    for (int rr = 0; rr < 4; ++rr){
      float m = inA ? mA[rr] : mB[rr];
      float e = __expf(sc[r][rr] - m);
      sc[r][rr] = e;
      if (inA) sA[rr] += e; else sB[rr] += e;
    }
  }
  #pragma unroll
  for (int m = 1; m < 16; m <<= 1){
    f32x4 t;
    t.x=__shfl_xor(sA.x,m); t.y=__shfl_xor(sA.y,m); t.z=__shfl_xor(sA.z,m); t.w=__shfl_xor(sA.w,m);
    sA += t;
    t.x=__shfl_xor(sB.x,m); t.y=__shfl_xor(sB.y,m); t.z=__shfl_xor(sB.z,m); t.w=__shfl_xor(sB.w,m);
    sB += t;
  }
  if (l16 < 4){
    float va = (l16==0)?sA.x:(l16==1)?sA.y:(l16==2)?sA.z:sA.w;
    float vb = (l16==0)?sB.x:(l16==1)?sB.y:(l16==2)?sB.z:sB.w;
    Sx[(itA*16 + quad*4 + l16)*2 + slot] = va;
    Sx[(itB*16 + quad*4 + l16)*2 + slot] = vb;
  }
  __syncthreads();                            // Vd writes fenced here
  f32x4 iA, iB;
  #pragma unroll
  for (int rr = 0; rr < 4; ++rr){
    float2 ta = *(const float2*)&Sx[(itA*16 + quad*4 + rr)*2];
    float2 tb = *(const float2*)&Sx[(itB*16 + quad*4 + rr)*2];
    iA[rr] = 1.f/(ta.x + ta.y); iB[rr] = 1.f/(tb.x + tb.y);
  }
  // probs into shared buffer (pitch 104)
  #pragma unroll
  for (int r = 0; r < 9; ++r){
    int tile = w*9 + r; int it = tile/6, pt = tile - it*6;
    int col = pt*16 + l16;
    bool inA = odd ? (r < 3) : (r < 6);
    #pragma unroll
    for (int rr = 0; rr < 4; ++rr){
      int row = it*16 + quad*4 + rr;
      float inv = inA ? iA[rr] : iB[rr];
      SsPb[row*104 + col] = f2bf(sc[r][rr] * inv);
    }
  }
  __syncthreads();
  // write probs [bh][i][j=jj][p]: 96 strided full-line 192B chunks
  unsigned short* ap = a_out + (size_t)bh*96*9216 + (size_t)jj*96;
  for (int g = tid; g < 1152; g += 256){
    int i = g / 12, cc = g - i*12;
    *(u16x8*)&ap[(size_t)i*9216 + cc*8] = *(const u16x8*)&SsPb[i*104 + cc*8];
  }
  // O2 = P(96i x 96p) @ V2(96p x 32d)
  #pragma unroll
  for (int r = 0; r < 3; ++r){
    int tile = w*3 + r; int it = tile >> 1, dt = tile & 1;
    f32x4 cc = {0.f,0.f,0.f,0.f};
    #pragma unroll
    for (int kp3 = 0; kp3 < 3; ++kp3){
      bf16x8 a = *(const bf16x8*)((const char*)SsPb + (it*16 + l16)*208 + kp3*64 + quad*16);
      const char* vb = (const char*)Vd + (dt*16 + l16)*200 + kp3*64 + quad*16;
      bf16x4 lo = *(const bf16x4*)vb;
      bf16x4 hi = *(const bf16x4*)(vb + 8);
      bf16x8 bb = __builtin_shufflevector(lo, hi, 0,1,2,3,4,5,6,7);
      cc = __builtin_amdgcn_mfma_f32_16x16x32_bf16(a, bb, cc, 0, 0, 0);
    }
    int d = dt*16 + l16;
    if (!last){
      #pragma unroll
      for (int rr = 0; rr < 4; ++rr){
        int i = it*16 + quad*4 + rr;
        xb[(((size_t)b*96 + i)*96 + jj)*256 + h*32 + d] = f2bf(cc[rr]);
      }
    } else {
      atomicAdd(&poolL[d], cc[0] + cc[1] + cc[2] + cc[3]);
    }
  }
  if (last){
    __syncthreads();
    if (tid < 32) atomicAdd(&poolAcc[b*256 + h*32 + tid], poolL[tid]);
  }
}

// ---------------- K7: O1 per (bh, ii); last==1: pool O1 only (no xb access) ----------------
__global__ __launch_bounds__(256) void k_attn1(const unsigned short* __restrict__ a_in,
                                               const unsigned short* __restrict__ qkv5,
                                               unsigned short* __restrict__ xb,
                                               float2* __restrict__ statsPart,
                                               float* __restrict__ poolAcc,
                                               int last){
  __shared__ unsigned short As[96*104], Vd[32*100];
  __shared__ float redS[256], redQ[256];
  __shared__ float poolL[32];
  int wg = blockIdx.x; int bh = wg/96, ii = wg - bh*96;
  int b = bh >> 3, h = bh & 7;
  int tid = threadIdx.x;
  if (tid < 32) poolL[tid] = 0.f;
  const unsigned short* vp = qkv5 + 3*(size_t)CE + ((size_t)bh*96 + ii)*3072;
  for (int g = tid; g < 768; g += 256){
    int r7 = g & 7, q4 = (g >> 3) & 7, a8 = g >> 6;
    int p = r7 + a8*8;
    u16x4 v = *(const u16x4*)&vp[p*32 + q4*4];
    int d0 = q4*4;
    Vd[(d0+0)*100 + p] = v.x; Vd[(d0+1)*100 + p] = v.y;
    Vd[(d0+2)*100 + p] = v.z; Vd[(d0+3)*100 + p] = v.w;
  }
  const unsigned short* ain = a_in + ((size_t)bh*96 + ii)*9216;   // contiguous
  for (int g = tid; g < 1152; g += 256){
    int j = g / 12, cc = g - j*12;
    *(u16x8*)&As[j*104 + cc*8] = *(const u16x8*)&ain[j*96 + cc*8];
  }
  __syncthreads();
  int w = tid >> 6, lane = tid & 63, quad = lane >> 4, l16 = lane & 15;
  float ls = 0.f, lq = 0.f;
  #pragma unroll
  for (int r = 0; r < 3; ++r){
    int tile = w*3 + r; int jt = tile >> 1, dt = tile & 1;
    f32x4 cc = {0.f,0.f,0.f,0.f};
    #pragma unroll
    for (int kp3 = 0; kp3 < 3; ++kp3){
      bf16x8 a = *(const bf16x8*)((const char*)As + (jt*16 + l16)*208 + kp3*64 + quad*16);
      const char* vb = (const char*)Vd + (dt*16 + l16)*200 + kp3*64 + quad*16;
      bf16x4 lo = *(const bf16x4*)vb;
      bf16x4 hi = *(const bf16x4*)(vb + 8);
      bf16x8 bb = __builtin_shufflevector(lo, hi, 0,1,2,3,4,5,6,7);
      cc = __builtin_amdgcn_mfma_f32_16x16x32_bf16(a, bb, cc, 0, 0, 0);
    }
    int d = dt*16 + l16;
    if (!last){
      #pragma unroll
      for (int rr = 0; rr < 4; ++rr){
        int j = jt*16 + quad*4 + rr;
        size_t xi = (((size_t)b*96 + ii)*96 + j)*256 + h*32 + d;
        float val = bf2f(xb[xi]) + cc[rr];
        xb[xi] = f2bf(val); ls += val; lq += val*val;
      }
    } else {
      atomicAdd(&poolL[d], cc[0] + cc[1] + cc[2] + cc[3]);
    }
  }
  if (!last){
    redS[tid] = ls; redQ[tid] = lq; __syncthreads();
    for (int o = 128; o > 0; o >>= 1){
      if (tid < o){ redS[tid] += redS[tid+o]; redQ[tid] += redQ[tid+o]; }
      __syncthreads();
    }
    if (tid == 0){
      float* pp = (float*)&statsPart[blockIdx.x & 63];
      atomicAdd(pp, redS[0]); atomicAdd(pp+1, redQ[0]);
    }
  } else {
    __syncthreads();
    if (tid < 32) atomicAdd(&poolAcc[b*256 + h*32 + tid], poolL[tid]);
  }
}

// ---------------- K9: head ----------------
__global__ __launch_bounds__(256) void k_head(const float* __restrict__ poolAcc,
                                              const float* __restrict__ hw,
                                              const float* __restrict__ hb,
                                              float* __restrict__ out){
  int b = blockIdx.x, t = threadIdx.x;
  __shared__ float xm[256];
  xm[t] = poolAcc[b*256 + t] * (1.0f/9216.0f);
  __syncthreads();
  float o = hb[t];
  for (int cc = 0; cc < 256; ++cc) o += xm[cc] * hw[t*256 + cc];
  out[b*256 + t] = o;
}

// ---------------- launch ----------------
extern "C" void kernel_launch(void* const* d_in, const int* in_sizes, int n_in,
                              void* d_out, int out_size, void* d_ws, size_t ws_size,
                              hipStream_t stream){
  (void)in_sizes; (void)n_in; (void)out_size; (void)ws_size;
  const int*   adj  = (const int*)d_in[0];
  const float* emb  = (const float*)d_in[1];
  const float* qkvw = (const float*)d_in[2];
  const float* hw   = (const float*)d_in[3];
  const float* hb   = (const float*)d_in[4];

  char* p = (char*)d_ws;
  unsigned short* xb   = (unsigned short*)p; p += (size_t)CE*2;            //  18.87 MB
  unsigned short* qkv5 = (unsigned short*)p; p += (size_t)5*CE*2;          //  94.37 MB
  unsigned short* s1   = (unsigned short*)p; p += (size_t)32*96*9216*2;    //  56.62 MB
  unsigned short* aP   = (unsigned short*)p; p += (size_t)32*96*9216*2;    //  56.62 MB
  unsigned short* wbf  = (unsigned short*)p; p += (size_t)4*1280*256*2;    //   2.62 MB
  float*          wsum = (float*)p;          p += (size_t)4*1280*4;        //  20 KB
  float2*         part = (float2*)p;         p += 4*64*sizeof(float2);
  float*          pool = (float*)p;          p += 1024*sizeof(float);

  k_init  <<<dim3(1),     dim3(256), 0, stream>>>((float*)part);
  k_gather<<<dim3(2304),  dim3(256), 0, stream>>>(adj, emb, xb, part);
  k_wconv <<<dim3(1280),  dim3(256), 0, stream>>>(qkvw, wbf, wsum);
  for (int l = 0; l < 4; ++l){
    int last = (l == 3) ? 1 : 0;
    k_gemm   <<<dim3(2880),    dim3(256), 0, stream>>>(xb, wbf + (size_t)l*1280*256,
                                                       wsum + l*1280, part + l*64, qkv5);
    k_scores1<<<dim3(3072),    dim3(256), 0, stream>>>(qkv5, s1);
    k_attn2  <<<dim3(3072),    dim3(256), 0, stream>>>(qkv5, s1, aP, xb, pool, last);
    k_attn1  <<<dim3(3072),    dim3(256), 0, stream>>>(aP, qkv5, xb,
                                                       part + (l+1 < 4 ? (l+1)*64 : 0),
                                                       pool, last);
  }
  k_head<<<dim3(4), dim3(256), 0, stream>>>(pool, hw, hb, (float*)d_out);
}

// Round 15
// 621.013 us; speedup vs baseline: 1.1672x; 1.0282x over previous
//
#include <hip/hip_runtime.h>

// ---------------- problem constants ----------------
#define B_ 4
#define N_ 96
#define C_ 256
#define NPAIR (B_*N_*N_)        // 36864 pair rows
#define CE (NPAIR*C_)           // 9437184 elements per qkv slab
#define SCALE 8.838834764831844f  // 50/sqrt(32)
#define CP 132                  // gemm C-stage LDS pitch (conflict-free)
// ws budget: 256 MiB. Usage ~229 MB. (Round-14 structure + attn2 XCD-affine grid.)

typedef __attribute__((ext_vector_type(4))) float f32x4;
typedef __attribute__((ext_vector_type(8))) __bf16 bf16x8;
typedef __attribute__((ext_vector_type(4))) __bf16 bf16x4;
typedef __attribute__((ext_vector_type(4))) unsigned short u16x4;
typedef __attribute__((ext_vector_type(8))) unsigned short u16x8;

__device__ __forceinline__ unsigned short f2bf(float f){
  __bf16 h = (__bf16)f;                      // RNE convert
  return __builtin_bit_cast(unsigned short, h);
}
__device__ __forceinline__ float bf2f(unsigned short u){
  union { unsigned int i; float f; } v; v.i = ((unsigned int)u) << 16; return v.f;
}
__device__ __forceinline__ f32x4 vmax4(f32x4 a, f32x4 b){
  f32x4 r; r.x=fmaxf(a.x,b.x); r.y=fmaxf(a.y,b.y); r.z=fmaxf(a.z,b.z); r.w=fmaxf(a.w,b.w); return r;
}

// async global->LDS, 16B per lane; lds dest = wave-uniform base + lane*16
__device__ __forceinline__ void gload16(const void* g, void* l){
  __builtin_amdgcn_global_load_lds((const __attribute__((address_space(1))) unsigned int*)g,
                                   (__attribute__((address_space(3))) unsigned int*)l,
                                   16, 0, 0);
}

// ---------------- K_init: zero stats partials (512 f) + pool acc (1024 f) ----------------
__global__ __launch_bounds__(256) void k_init(float* __restrict__ z){
  for (int i = threadIdx.x; i < 1536; i += 256) z[i] = 0.f;
}

// ---------------- K0: xb = bf16(emb[adj]) + stats partials (fp32-accurate) ----------------
__global__ __launch_bounds__(256) void k_gather(const int* __restrict__ adj,
                                                const float* __restrict__ emb,
                                                unsigned short* __restrict__ xb,
                                                float2* __restrict__ part){
  int tid = threadIdx.x;
  int lp = tid >> 4, lane16 = tid & 15;
  int pair = blockIdx.x*16 + lp;
  int row = adj[pair];
  const f32x4* src = (const f32x4*)(emb + (size_t)row*C_);
  u16x4*       dst = (u16x4*)(xb + (size_t)pair*C_);
  float s = 0.f, q = 0.f;
  for (int v = 0; v < 4; ++v){
    f32x4 t = src[v*16 + lane16];
    u16x4 o;
    o.x = f2bf(t.x); o.y = f2bf(t.y); o.z = f2bf(t.z); o.w = f2bf(t.w);
    dst[v*16 + lane16] = o;
    s += t.x + t.y + t.z + t.w;
    q += t.x*t.x + t.y*t.y + t.z*t.z + t.w*t.w;
  }
  __shared__ float rs[256], rq[256];
  rs[tid] = s; rq[tid] = q; __syncthreads();
  for (int o = 128; o > 0; o >>= 1){
    if (tid < o){ rs[tid] += rs[tid+o]; rq[tid] += rq[tid+o]; }
    __syncthreads();
  }
  if (tid == 0){
    float* pp = (float*)&part[blockIdx.x & 63];
    atomicAdd(pp, rs[0]); atomicAdd(pp+1, rq[0]);
  }
}

// ---------------- K0b: weights fp32->bf16 + per-row fp32 sums (for norm folding) ----------------
__global__ __launch_bounds__(256) void k_wconv(const float* __restrict__ w,
                                               unsigned short* __restrict__ wb,
                                               float* __restrict__ wsum){
  int row  = blockIdx.x*4 + (threadIdx.x >> 6);
  int lane = threadIdx.x & 63;
  f32x4 v = ((const f32x4*)(w + (size_t)row*256))[lane];
  u16x4 o;
  o.x = f2bf(v.x); o.y = f2bf(v.y); o.z = f2bf(v.z); o.w = f2bf(v.w);
  ((u16x4*)(wb + (size_t)row*256))[lane] = o;
  float s = v.x + v.y + v.z + v.w;
  for (int m = 32; m > 0; m >>= 1) s += __shfl_down(s, m);
  if (lane == 0) wsum[row] = s;
}

// ---------------- K4: qkv GEMM, XCD-swizzled grid, folded norm, LDS-staged epilogue ----------------
__global__ __launch_bounds__(256) void k_gemm(const unsigned short* __restrict__ Xb,
                                              const unsigned short* __restrict__ W,
                                              const float* __restrict__ wsum_l,
                                              const float2* __restrict__ part,
                                              unsigned short* __restrict__ qkv5){
  __shared__ unsigned short smem[128*CP];    // As|Bs carved during K-loop
  unsigned short* As = smem;
  unsigned short* Bs = smem + 128*64;
  const int tid = threadIdx.x;
  const int w = tid >> 6, lane = tid & 63;
  const int quad = lane >> 4, l16 = lane & 15;
  const int L = blockIdx.x;
  const int xcd = L & 7, rest = L >> 3;
  const int nt = rest % 10, kt2 = rest / 10;
  const int m0 = (xcd + 8*kt2) * 128, n0 = nt * 128;
  const int mw = (w & 1) * 64, nw = (w >> 1) * 64;
  double S = 0.0, Q = 0.0;
  for (int i = 0; i < 64; ++i){ float2 pp = part[i]; S += (double)pp.x; Q += (double)pp.y; }
  const float mean = (float)(S / (double)CE);
  const float rstd = (float)(1.0 / sqrt((Q - S*S/(double)CE) / (double)(CE - 1)));
  f32x4 acc[4][4] = {};

  for (int kt = 0; kt < 256; kt += 64){
    const int rbase = w * 32;
    const int rowoff = lane >> 3;
    const int kg = (lane & 7) ^ rowoff;
    for (int i8 = 0; i8 < 4; ++i8){
      int row = rbase + i8*8 + rowoff;
      gload16(Xb + (size_t)(m0+row)*256 + kt + kg*8, &As[(rbase + i8*8)*64]);
      gload16(W  + (size_t)(n0+row)*256 + kt + kg*8, &Bs[(rbase + i8*8)*64]);
    }
    __syncthreads();
    for (int ks = 0; ks < 2; ++ks){
      bf16x8 af[4], bf[4];
      for (int t4 = 0; t4 < 4; ++t4){
        int rm = mw + t4*16 + l16;
        af[t4] = *(const bf16x8*)((const char*)As + rm*128 + ((((ks<<2)|quad) ^ (rm&7))*16));
        int rn = nw + t4*16 + l16;
        bf[t4] = *(const bf16x8*)((const char*)Bs + rn*128 + ((((ks<<2)|quad) ^ (rn&7))*16));
      }
      for (int mi = 0; mi < 4; ++mi)
        for (int ni = 0; ni < 4; ++ni)
          acc[mi][ni] = __builtin_amdgcn_mfma_f32_16x16x32_bf16(af[mi], bf[ni], acc[mi][ni], 0, 0, 0);
    }
    __syncthreads();
  }

  float ws[4];
  #pragma unroll
  for (int ni = 0; ni < 4; ++ni) ws[ni] = wsum_l[n0 + nw + ni*16 + l16];
  for (int mi = 0; mi < 4; ++mi)
    for (int ni = 0; ni < 4; ++ni)
      for (int r = 0; r < 4; ++r){
        int row = mw + mi*16 + quad*4 + r;
        int col = nw + ni*16 + l16;
        float val = rstd*(acc[mi][ni][r] - mean*ws[ni]);
        smem[row*CP + col] = f2bf(val);
      }
  __syncthreads();

  const int t_slab = n0 >> 8;
  const int hbase  = (n0 >> 5) & 7;
  unsigned short* slab = qkv5 + (size_t)t_slab*CE;
  const int trow = tid >> 4;
  const int tcol = (tid & 15) * 8;
  const int h  = hbase + (tcol >> 5);
  const int dd = tcol & 31;
  for (int pass = 0; pass < 8; ++pass){
    int row = pass*16 + trow;
    int gm = m0 + row;
    int b = gm / 9216; int rem = gm - b*9216;
    int ii = rem / 96, jj = rem - (rem/96)*96;
    u16x8 vv = *(const u16x8*)&smem[row*CP + tcol];
    *(u16x8*)&slab[(((size_t)(b*8+h)*96 + ii)*96 + jj)*32 + dd] = vv;
  }
}

// ---------------- K5: branch-1 scores; s1 layout [bh][j][i][p] (fp16) ----------------
__global__ __launch_bounds__(256) void k_scores1(const unsigned short* __restrict__ qkv5,
                                                 unsigned short* __restrict__ s1){
  __shared__ unsigned short Qs[96*40], Ks[96*40];
  __shared__ unsigned short Ss[96*100];
  int wg = blockIdx.x; int bh = wg/96, ic = wg - bh*96;   // ic = i
  int tid = threadIdx.x;
  size_t gslab = (size_t)wg*3072;
  const unsigned short* qp = qkv5 + 0*(size_t)CE + gslab;
  const unsigned short* kp = qkv5 + 1*(size_t)CE + gslab;
  for (int g = tid; g < 768; g += 256){
    int j = g >> 3, q4 = g & 7;
    *(u16x4*)&Qs[j*40 + q4*4] = *(const u16x4*)&qp[j*32 + q4*4];
    *(u16x4*)&Ks[j*40 + q4*4] = *(const u16x4*)&kp[j*32 + q4*4];
  }
  __syncthreads();
  int w = tid >> 6, lane = tid & 63, quad = lane >> 4, l16 = lane & 15;
  #pragma unroll
  for (int r = 0; r < 9; ++r){
    int tile = w*9 + r; int jt = tile/6, pt = tile - jt*6;
    bf16x8 a = *(const bf16x8*)((const char*)Qs + (jt*16 + l16)*80 + quad*16);
    bf16x8 b = *(const bf16x8*)((const char*)Ks + (pt*16 + l16)*80 + quad*16);
    f32x4 cc = {0.f,0.f,0.f,0.f};
    cc = __builtin_amdgcn_mfma_f32_16x16x32_bf16(a, b, cc, 0, 0, 0);
    int col = pt*16 + l16;
    #pragma unroll
    for (int rr = 0; rr < 4; ++rr){
      int row = jt*16 + quad*4 + rr;
      _Float16 hv = (_Float16)(cc[rr] * SCALE);
      Ss[row*100 + col] = __builtin_bit_cast(unsigned short, hv);
    }
  }
  __syncthreads();
  for (int g = tid; g < 1152; g += 256){
    int j = g / 12, c8 = g - j*12;
    *(u16x8*)&s1[((size_t)(bh*96 + j))*9216 + ic*96 + c8*8] = *(const u16x8*)&Ss[j*100 + c8*8];
  }
}

// ---------------- K6: branch-2 scores + register softmax + O2, per (bh, jj) ----------------
// XCD-affine grid: all 96 jj of a bh land on one XCD -> adjacent-jj 128B-line
// sharing of q/k2/v2 (layout [bh][p][jj][d]) stays within one L2.
__global__ __launch_bounds__(256) void k_attn2(const unsigned short* __restrict__ qkv5,
                                               const unsigned short* __restrict__ s1,
                                               unsigned short* __restrict__ a_out,
                                               unsigned short* __restrict__ xb,
                                               float* __restrict__ poolAcc,
                                               int last){
  __shared__ unsigned short Qs[96*40];       // phase1: Q rows; phase2: Vd alias
  __shared__ unsigned short Ks[96*40];
  __shared__ unsigned short SsPb[96*104];    // phase1: s1 pitch 100; phase2: probs bf16 pitch 104
  __shared__ float Mx[192], Sx[192];
  __shared__ float poolL[32];
  unsigned short* Vd = Qs;                   // alias (disjoint lifetime)
  const int L = blockIdx.x;
  const int virt = (L & 7)*384 + (L >> 3);   // XCD k <- virt in [384k, 384k+384)
  int bh = virt/96, jj = virt - bh*96;
  int b = bh >> 3, h = bh & 7;
  int tid = threadIdx.x;
  int w = tid >> 6, lane = tid & 63, quad = lane >> 4, l16 = lane & 15;
  const unsigned short* qn  = qkv5 + 0*(size_t)CE;
  const unsigned short* k2n = qkv5 + 2*(size_t)CE;
  const unsigned short* v2n = qkv5 + 4*(size_t)CE;
  if (tid < 192){ Mx[tid] = -1e30f; Sx[tid] = 0.f; }
  if (tid < 32) poolL[tid] = 0.f;
  // stage s1 (contiguous 18432B) -> LDS pitch 100 (rows are exactly 12 u16x8 chunks)
  const unsigned short* s1g = s1 + ((size_t)bh*96 + jj)*9216;
  for (int g = tid; g < 1152; g += 256){
    int i = g / 12, c8 = g - i*12;
    *(u16x8*)&SsPb[i*100 + c8*8] = *(const u16x8*)&s1g[i*96 + c8*8];
  }
  // stage Q/K2 (q4-major lane map); V2 deferred
  for (int g = tid; g < 768; g += 256){
    int r7 = g & 7, q4 = (g >> 3) & 7, a8 = g >> 6;
    int p = r7 + a8*8;
    size_t base = (((size_t)bh*96 + p)*96 + jj)*32 + q4*4;
    *(u16x4*)&Qs[p*40 + q4*4] = *(const u16x4*)&qn[base];
    *(u16x4*)&Ks[p*40 + q4*4] = *(const u16x4*)&k2n[base];
  }
  __syncthreads();
  f32x4 sc[9];
  #pragma unroll
  for (int r = 0; r < 9; ++r){
    int tile = w*9 + r; int it = tile/6, pt = tile - it*6;
    bf16x8 a = *(const bf16x8*)((const char*)Qs + (it*16 + l16)*80 + quad*16);
    bf16x8 bb = *(const bf16x8*)((const char*)Ks + (pt*16 + l16)*80 + quad*16);
    f32x4 cc = {0.f,0.f,0.f,0.f};
    cc = __builtin_amdgcn_mfma_f32_16x16x32_bf16(a, bb, cc, 0, 0, 0);
    int col = pt*16 + l16;
    #pragma unroll
    for (int rr = 0; rr < 4; ++rr){
      int row = it*16 + quad*4 + rr;
      _Float16 hv = __builtin_bit_cast(_Float16, SsPb[row*100 + col]);
      sc[r][rr] = cc[rr]*SCALE + (float)hv;
    }
  }
  const bool odd = (w & 1);
  const int itA = (w*9)/6, itB = itA + 1;
  const int slot = w & 1;
  f32x4 vA = {-1e30f,-1e30f,-1e30f,-1e30f}, vB = vA;
  #pragma unroll
  for (int r = 0; r < 9; ++r){
    bool inA = odd ? (r < 3) : (r < 6);
    if (inA) vA = vmax4(vA, sc[r]); else vB = vmax4(vB, sc[r]);
  }
  #pragma unroll
  for (int m = 1; m < 16; m <<= 1){
    f32x4 t;
    t.x=__shfl_xor(vA.x,m); t.y=__shfl_xor(vA.y,m); t.z=__shfl_xor(vA.z,m); t.w=__shfl_xor(vA.w,m);
    vA = vmax4(vA, t);
    t.x=__shfl_xor(vB.x,m); t.y=__shfl_xor(vB.y,m); t.z=__shfl_xor(vB.z,m); t.w=__shfl_xor(vB.w,m);
    vB = vmax4(vB, t);
  }
  if (l16 < 4){
    float va = (l16==0)?vA.x:(l16==1)?vA.y:(l16==2)?vA.z:vA.w;
    float vb = (l16==0)?vB.x:(l16==1)?vB.y:(l16==2)?vB.z:vB.w;
    Mx[(itA*16 + quad*4 + l16)*2 + slot] = va;
    Mx[(itB*16 + quad*4 + l16)*2 + slot] = vb;
  }
  __syncthreads();                            // all Qs/Ks reads complete here
  // late-stage V2 into the Qs alias (overlaps with softmax below)
  for (int g = tid; g < 768; g += 256){
    int r7 = g & 7, q4 = (g >> 3) & 7, a8 = g >> 6;
    int p = r7 + a8*8;
    u16x4 v = *(const u16x4*)&v2n[(((size_t)bh*96 + p)*96 + jj)*32 + q4*4];
    int d0 = q4*4;
    Vd[(d0+0)*100 + p] = v.x; Vd[(d0+1)*100 + p] = v.y;
    Vd[(d0+2)*100 + p] = v.z; Vd[(d0+3)*100 + p] = v.w;
  }
  f32x4 mA, mB;
  #pragma unroll
  for (int rr = 0; rr < 4; ++rr){
    float2 ta = *(const float2*)&Mx[(itA*16 + quad*4 + rr)*2];
    float2 tb = *(const float2*)&Mx[(itB*16 + quad*4 + rr)*2];
    mA[rr] = fmaxf(ta.x, ta.y); mB[rr] = fmaxf(tb.x, tb.y);
  }
  f32x4 sA = {0.f,0.f,0.f,0.f}, sB = {0.f,0.f,0.f,0.f};
  #pragma unroll
  for (int r = 0; r < 9; ++r){
    bool inA = odd ? (r < 3) : (r < 6);
    #pragma unroll
    for (int rr = 0; rr < 4; ++rr){
      float m = inA ? mA[rr] : mB[rr];
      float e = __expf(sc[r][rr] - m);
      sc[r][rr] = e;
      if (inA) sA[rr] += e; else sB[rr] += e;
    }
  }
  #pragma unroll
  for (int m = 1; m < 16; m <<= 1){
    f32x4 t;
    t.x=__shfl_xor(sA.x,m); t.y=__shfl_xor(sA.y,m); t.z=__shfl_xor(sA.z,m); t.w=__shfl_xor(sA.w,m);
    sA += t;
    t.x=__shfl_xor(sB.x,m); t.y=__shfl_xor(sB.y,m); t.z=__shfl_xor(sB.z,m); t.w=__shfl_xor(sB.w,m);
    sB += t;
  }
  if (l16 < 4){
    float va = (l16==0)?sA.x:(l16==1)?sA.y:(l16==2)?sA.z:sA.w;
    float vb = (l16==0)?sB.x:(l16==1)?sB.y:(l16==2)?sB.z:sB.w;
    Sx[(itA*16 + quad*4 + l16)*2 + slot] = va;
    Sx[(itB*16 + quad*4 + l16)*2 + slot] = vb;
  }
  __syncthreads();                            // Vd writes fenced here
  f32x4 iA, iB;
  #pragma unroll
  for (int rr = 0; rr < 4; ++rr){
    float2 ta = *(const float2*)&Sx[(itA*16 + quad*4 + rr)*2];
    float2 tb = *(const float2*)&Sx[(itB*16 + quad*4 + rr)*2];
    iA[rr] = 1.f/(ta.x + ta.y); iB[rr] = 1.f/(tb.x + tb.y);
  }
  // probs into shared buffer (pitch 104)
  #pragma unroll
  for (int r = 0; r < 9; ++r){
    int tile = w*9 + r; int it = tile/6, pt = tile - it*6;
    int col = pt*16 + l16;
    bool inA = odd ? (r < 3) : (r < 6);
    #pragma unroll
    for (int rr = 0; rr < 4; ++rr){
      int row = it*16 + quad*4 + rr;
      float inv = inA ? iA[rr] : iB[rr];
      SsPb[row*104 + col] = f2bf(sc[r][rr] * inv);
    }
  }
  __syncthreads();
  // write probs [bh][i][j=jj][p]: 96 strided full-line 192B chunks
  unsigned short* ap = a_out + (size_t)bh*96*9216 + (size_t)jj*96;
  for (int g = tid; g < 1152; g += 256){
    int i = g / 12, cc = g - i*12;
    *(u16x8*)&ap[(size_t)i*9216 + cc*8] = *(const u16x8*)&SsPb[i*104 + cc*8];
  }
  // O2 = P(96i x 96p) @ V2(96p x 32d)
  #pragma unroll
  for (int r = 0; r < 3; ++r){
    int tile = w*3 + r; int it = tile >> 1, dt = tile & 1;
    f32x4 cc = {0.f,0.f,0.f,0.f};
    #pragma unroll
    for (int kp3 = 0; kp3 < 3; ++kp3){
      bf16x8 a = *(const bf16x8*)((const char*)SsPb + (it*16 + l16)*208 + kp3*64 + quad*16);
      const char* vb = (const char*)Vd + (dt*16 + l16)*200 + kp3*64 + quad*16;
      bf16x4 lo = *(const bf16x4*)vb;
      bf16x4 hi = *(const bf16x4*)(vb + 8);
      bf16x8 bb = __builtin_shufflevector(lo, hi, 0,1,2,3,4,5,6,7);
      cc = __builtin_amdgcn_mfma_f32_16x16x32_bf16(a, bb, cc, 0, 0, 0);
    }
    int d = dt*16 + l16;
    if (!last){
      #pragma unroll
      for (int rr = 0; rr < 4; ++rr){
        int i = it*16 + quad*4 + rr;
        xb[(((size_t)b*96 + i)*96 + jj)*256 + h*32 + d] = f2bf(cc[rr]);
      }
    } else {
      atomicAdd(&poolL[d], cc[0] + cc[1] + cc[2] + cc[3]);
    }
  }
  if (last){
    __syncthreads();
    if (tid < 32) atomicAdd(&poolAcc[b*256 + h*32 + tid], poolL[tid]);
  }
}

// ---------------- K7: O1 per (bh, ii); last==1: pool O1 only (no xb access) ----------------
__global__ __launch_bounds__(256) void k_attn1(const unsigned short* __restrict__ a_in,
                                               const unsigned short* __restrict__ qkv5,
                                               unsigned short* __restrict__ xb,
                                               float2* __restrict__ statsPart,
                                               float* __restrict__ poolAcc,
                                               int last){
  __shared__ unsigned short As[96*104], Vd[32*100];
  __shared__ float redS[256], redQ[256];
  __shared__ float poolL[32];
  int wg = blockIdx.x; int bh = wg/96, ii = wg - bh*96;
  int b = bh >> 3, h = bh & 7;
  int tid = threadIdx.x;
  if (tid < 32) poolL[tid] = 0.f;
  const unsigned short* vp = qkv5 + 3*(size_t)CE + ((size_t)bh*96 + ii)*3072;
  for (int g = tid; g < 768; g += 256){
    int r7 = g & 7, q4 = (g >> 3) & 7, a8 = g >> 6;
    int p = r7 + a8*8;
    u16x4 v = *(const u16x4*)&vp[p*32 + q4*4];
    int d0 = q4*4;
    Vd[(d0+0)*100 + p] = v.x; Vd[(d0+1)*100 + p] = v.y;
    Vd[(d0+2)*100 + p] = v.z; Vd[(d0+3)*100 + p] = v.w;
  }
  const unsigned short* ain = a_in + ((size_t)bh*96 + ii)*9216;   // contiguous
  for (int g = tid; g < 1152; g += 256){
    int j = g / 12, cc = g - j*12;
    *(u16x8*)&As[j*104 + cc*8] = *(const u16x8*)&ain[j*96 + cc*8];
  }
  __syncthreads();
  int w = tid >> 6, lane = tid & 63, quad = lane >> 4, l16 = lane & 15;
  float ls = 0.f, lq = 0.f;
  #pragma unroll
  for (int r = 0; r < 3; ++r){
    int tile = w*3 + r; int jt = tile >> 1, dt = tile & 1;
    f32x4 cc = {0.f,0.f,0.f,0.f};
    #pragma unroll
    for (int kp3 = 0; kp3 < 3; ++kp3){
      bf16x8 a = *(const bf16x8*)((const char*)As + (jt*16 + l16)*208 + kp3*64 + quad*16);
      const char* vb = (const char*)Vd + (dt*16 + l16)*200 + kp3*64 + quad*16;
      bf16x4 lo = *(const bf16x4*)vb;
      bf16x4 hi = *(const bf16x4*)(vb + 8);
      bf16x8 bb = __builtin_shufflevector(lo, hi, 0,1,2,3,4,5,6,7);
      cc = __builtin_amdgcn_mfma_f32_16x16x32_bf16(a, bb, cc, 0, 0, 0);
    }
    int d = dt*16 + l16;
    if (!last){
      #pragma unroll
      for (int rr = 0; rr < 4; ++rr){
        int j = jt*16 + quad*4 + rr;
        size_t xi = (((size_t)b*96 + ii)*96 + j)*256 + h*32 + d;
        float val = bf2f(xb[xi]) + cc[rr];
        xb[xi] = f2bf(val); ls += val; lq += val*val;
      }
    } else {
      atomicAdd(&poolL[d], cc[0] + cc[1] + cc[2] + cc[3]);
    }
  }
  if (!last){
    redS[tid] = ls; redQ[tid] = lq; __syncthreads();
    for (int o = 128; o > 0; o >>= 1){
      if (tid < o){ redS[tid] += redS[tid+o]; redQ[tid] += redQ[tid+o]; }
      __syncthreads();
    }
    if (tid == 0){
      float* pp = (float*)&statsPart[blockIdx.x & 63];
      atomicAdd(pp, redS[0]); atomicAdd(pp+1, redQ[0]);
    }
  } else {
    __syncthreads();
    if (tid < 32) atomicAdd(&poolAcc[b*256 + h*32 + tid], poolL[tid]);
  }
}

// ---------------- K9: head ----------------
__global__ __launch_bounds__(256) void k_head(const float* __restrict__ poolAcc,
                                              const float* __restrict__ hw,
                                              const float* __restrict__ hb,
                                              float* __restrict__ out){
  int b = blockIdx.x, t = threadIdx.x;
  __shared__ float xm[256];
  xm[t] = poolAcc[b*256 + t] * (1.0f/9216.0f);
  __syncthreads();
  float o = hb[t];
  for (int cc = 0; cc < 256; ++cc) o += xm[cc] * hw[t*256 + cc];
  out[b*256 + t] = o;
}

// ---------------- launch ----------------
extern "C" void kernel_launch(void* const* d_in, const int* in_sizes, int n_in,
                              void* d_out, int out_size, void* d_ws, size_t ws_size,
                              hipStream_t stream){
  (void)in_sizes; (void)n_in; (void)out_size; (void)ws_size;
  const int*   adj  = (const int*)d_in[0];
  const float* emb  = (const float*)d_in[1];
  const float* qkvw = (const float*)d_in[2];
  const float* hw   = (const float*)d_in[3];
  const float* hb   = (const float*)d_in[4];

  char* p = (char*)d_ws;
  unsigned short* xb   = (unsigned short*)p; p += (size_t)CE*2;            //  18.87 MB
  unsigned short* qkv5 = (unsigned short*)p; p += (size_t)5*CE*2;          //  94.37 MB
  unsigned short* s1   = (unsigned short*)p; p += (size_t)32*96*9216*2;    //  56.62 MB
  unsigned short* aP   = (unsigned short*)p; p += (size_t)32*96*9216*2;    //  56.62 MB
  unsigned short* wbf  = (unsigned short*)p; p += (size_t)4*1280*256*2;    //   2.62 MB
  float*          wsum = (float*)p;          p += (size_t)4*1280*4;        //  20 KB
  float2*         part = (float2*)p;         p += 4*64*sizeof(float2);
  float*          pool = (float*)p;          p += 1024*sizeof(float);

  k_init  <<<dim3(1),     dim3(256), 0, stream>>>((float*)part);
  k_gather<<<dim3(2304),  dim3(256), 0, stream>>>(adj, emb, xb, part);
  k_wconv <<<dim3(1280),  dim3(256), 0, stream>>>(qkvw, wbf, wsum);
  for (int l = 0; l < 4; ++l){
    int last = (l == 3) ? 1 : 0;
    k_gemm   <<<dim3(2880),    dim3(256), 0, stream>>>(xb, wbf + (size_t)l*1280*256,
                                                       wsum + l*1280, part + l*64, qkv5);
    k_scores1<<<dim3(3072),    dim3(256), 0, stream>>>(qkv5, s1);
    k_attn2  <<<dim3(3072),    dim3(256), 0, stream>>>(qkv5, s1, aP, xb, pool, last);
    k_attn1  <<<dim3(3072),    dim3(256), 0, stream>>>(aP, qkv5, xb,
                                                       part + (l+1 < 4 ? (l+1)*64 : 0),
                                                       pool, last);
  }
  k_head<<<dim3(4), dim3(256), 0, stream>>>(pool, hw, hb, (float*)d_out);
}